// Round 4
// baseline (13715.392 us; speedup 1.0000x reference)
//
#include <hip/hip_runtime.h>
#include <math.h>

#define N 4096
#define STEPS 16384
#define WIN 32                 // steps resolved per barrier pair
#define NWIN (STEPS / WIN)
#define MBLK 1024
#define SBS 36   // padded stride (floats) for 32-wide coupling blocks (float4-aligned)
#define NW (MBLK - 64)    // 960 worker threads (waves 1..15)
#define XBASE (4 * NW)    // 3840: first 3840 field elements owned 4-per-worker
#define NX (N - XBASE)    // 256 extras owned 1-each by tid 64..319

// Workgroup barrier that does NOT drain vmcnt (LDS-only ordering between phases).
__device__ __forceinline__ void lgkm_barrier() {
  asm volatile("s_waitcnt lgkmcnt(0)\n\ts_barrier" ::: "memory");
}

// ---- prep: thr[t] = atanh(2u-1) in fp64; lastocc[t] = no later same-idx in window ----
__global__ __launch_bounds__(256) void pre_kernel(const float* __restrict__ u,
                                                  const int* __restrict__ idx,
                                                  double* __restrict__ thr,
                                                  int* __restrict__ lastocc) {
  int t = blockIdx.x * 256 + threadIdx.x;
  if (t < STEPS) {
    float r = 2.0f * u[t] - 1.0f;          // exact same fp32 rounding as reference
    double rd = (double)r;
    thr[t] = 0.5 * log((1.0 + rd) / (1.0 - rd));   // r=-1 -> -inf (tie->+1 matches ref)
    int cbase = t & ~(WIN - 1);
    int my = idx[t];
    int lo = 1;
    for (int tt = (t & (WIN - 1)) + 1; tt < WIN; ++tt)
      if (idx[cbase + tt] == my) { lo = 0; break; }
    lastocc[t] = lo;
  }
}

// ---- initial field: I0[row] = sum_k J[row,k]*m0[k] + h[row], fp64 accumulate ----
__global__ __launch_bounds__(256) void init_field_kernel(const float* __restrict__ J,
                                                         const float* __restrict__ h,
                                                         const float* __restrict__ m0,
                                                         double* __restrict__ I) {
  __shared__ double red[256];
  int row = blockIdx.x;
  const float4* Jr = (const float4*)(J + (size_t)row * N);
  const float4* mv = (const float4*)m0;
  double acc = 0.0;
  for (int q = threadIdx.x; q < N / 4; q += 256) {
    float4 a = Jr[q];
    float4 b = mv[q];
    acc += (double)(a.x * b.x) + (double)(a.y * b.y) +
           (double)(a.z * b.z) + (double)(a.w * b.w);
  }
  red[threadIdx.x] = acc;
  __syncthreads();
  for (int s = 128; s > 0; s >>= 1) {
    if (threadIdx.x < s) red[threadIdx.x] += red[threadIdx.x + s];
    __syncthreads();
  }
  if (threadIdx.x == 0) I[row] = red[0] + (double)h[row];
}

// ---- deep-pipelined window-resolved Glauber chain: 1 workgroup, 1024 threads ----
// Serial two-phase structure (workers parked during the resolve), but every
// latency exposure is pipelined out:
//  P1(k): wave0 resolves window k (field_lds lags 2 windows; xacc supplies the
//         window k-1 cross terms via SX), publishes flips, issues the G(k+2)
//         block gather + step-data loads. Workers park at the barrier.
//  P2(k): wave0 stores G(k+2) (full-window slack) and prefetches ST/SX register
//         fragments for resolve(k+1). Workers FMA-apply window k-1's flips
//         (rows preloaded in P2(k-1): zero exposure) and ISSUE loads for
//         window k's flip rows (consumed next P2).
// G(w) block = rows J[idx(w)] x cols [idx(w) | idx(w-1)]: ST(w) half (in-window
// couplings, via symmetry) and SX(w-1->w) half (cross-window corrections).
__global__ __launch_bounds__(MBLK) void pbit_kernel(const float* __restrict__ J,
                                                    const float* __restrict__ m0,
                                                    const int* __restrict__ idx,
                                                    const double* __restrict__ thr,
                                                    const int* __restrict__ lastocc,
                                                    const double* __restrict__ I0,
                                                    float* __restrict__ out) {
  __shared__ __align__(16) double field_lds[N];        // 32 KB master field
  __shared__ __align__(16) float m_lds[N];             // 16 KB spins
  __shared__ __align__(16) float bufST[2][WIN * SBS];  // ST[r*SBS+c] = J[idx_w[r]][idx_w[c]]
  __shared__ __align__(16) float bufSX[2][WIN * SBS];  // SX[r*SBS+c] = J[idx_w[r]][idx_{w-1}[c]]
  __shared__ __align__(16) int   pubi_lds[2][WIN];     // double-buffered flip rows
  __shared__ __align__(16) float pubd_lds[2][WIN];     // double-buffered deltas (+/-2)
  __shared__ int pubF_lds[2];                          // flip counts

  const int tid = threadIdx.x;

  // field_lds init by launch layout
  {
    const double* ip = I0 + 4 * tid;
    double a = ip[0], b = ip[1], c = ip[2], d = ip[3];
    *(double2*)(field_lds + 4 * tid + 0) = make_double2(a, b);
    *(double2*)(field_lds + 4 * tid + 2) = make_double2(c, d);
  }
  ((float4*)m_lds)[tid] = ((const float4*)m0)[tid];
  if (tid == 0) { pubF_lds[0] = 0; pubF_lds[1] = 0; }

  const int t32 = tid & 31;         // step slot within window (lanes 32-63 duplicate)
  const int jrow = tid >> 1;        // gather row slot (wave0: 0..31)
  const int half = (tid & 1) * 16;  // gather col half

  // ---- worker (waves 1-15) field ownership: fp64 registers + LDS write-through ----
  const bool isw = (tid >= 64);
  const int wid = isw ? (tid - 64) : 0;
  const bool isx = isw && (tid < 64 + NX);
  double i0 = 0.0, i1 = 0.0, i2 = 0.0, i3 = 0.0, i4 = 0.0;
  if (isw) {
    const double* ip = I0 + 4 * wid;
    i0 = ip[0]; i1 = ip[1]; i2 = ip[2]; i3 = ip[3];
    if (isx) i4 = I0[XBASE + wid];
  }
  const float* Jb = J + 4 * (size_t)wid;
  const float* Jx = J + XBASE + (size_t)wid;
  float4 rv[WIN];       // staged flip-row slices (loaded P2(k), consumed P2(k+1))
  float rxv[WIN];       // staged extra-element values (isx threads)

  // ---- wave0 pipeline registers ----
  int mi = 0, ni = 0, p2i = 0, mlo = 0, nlo = 0, p2lo = 0;
  double mt = 0.0, nt = 0.0, p2t = 0.0;
  float gvS[16], gvX[16];           // in-flight G block (issued P1(k), stored P2(k))
  double xacc = 0.0;                // cross-correction for next window, per lane
  float4 s0, s1, s2, s3, s4, s5, s6, s7;   // ST register row (this window)
  float4 x0, x1, x2, x3, x4, x5, x6, x7;   // SX register row (this->next window)
  s0=s1=s2=s3=s4=s5=s6=s7=make_float4(0.f,0.f,0.f,0.f);
  x0=x1=x2=x3=x4=x5=x6=x7=make_float4(0.f,0.f,0.f,0.f);

  if (tid < 64) {
    mi  = idx[t32];           mt  = thr[t32];           mlo  = lastocc[t32];
    ni  = idx[WIN + t32];     nt  = thr[WIN + t32];     nlo  = lastocc[WIN + t32];
    p2i = idx[2 * WIN + t32]; p2t = thr[2 * WIN + t32]; p2lo = lastocc[2 * WIN + t32];
    // sync G(0): rows idx0, ST cols idx0 -> bufST[0]  (SX half unused)
    {
      int r0 = __shfl(mi, jrow);
      const float* Jr = J + (size_t)r0 * N;
#pragma unroll
      for (int q = 0; q < 16; ++q) {
        int c = __shfl(mi, half + q);
        bufST[0][jrow * SBS + half + q] = Jr[c];
      }
    }
    // sync G(1): rows idx1, ST cols idx1 -> bufST[1], SX cols idx0 -> bufSX[1]
    {
      int r1 = __shfl(ni, jrow);
      const float* Jg = J + (size_t)r1 * N;
#pragma unroll
      for (int q = 0; q < 16; ++q) {
        int c = __shfl(ni, half + q);
        bufST[1][jrow * SBS + half + q] = Jg[c];
      }
#pragma unroll
      for (int q = 0; q < 16; ++q) {
        int c = __shfl(mi, half + q);
        bufSX[1][jrow * SBS + half + q] = Jg[c];
      }
    }
  }
  __syncthreads();
  if (tid < 64) {
    // fragments for resolve(0): ST(0) and SX(0->1)
    const float* sp = &bufST[0][(size_t)t32 * SBS];
    s0 = *(const float4*)(sp + 0);  s1 = *(const float4*)(sp + 4);
    s2 = *(const float4*)(sp + 8);  s3 = *(const float4*)(sp + 12);
    s4 = *(const float4*)(sp + 16); s5 = *(const float4*)(sp + 20);
    s6 = *(const float4*)(sp + 24); s7 = *(const float4*)(sp + 28);
    const float* xp = &bufSX[1][(size_t)t32 * SBS];
    x0 = *(const float4*)(xp + 0);  x1 = *(const float4*)(xp + 4);
    x2 = *(const float4*)(xp + 8);  x3 = *(const float4*)(xp + 12);
    x4 = *(const float4*)(xp + 16); x5 = *(const float4*)(xp + 20);
    x6 = *(const float4*)(xp + 24); x7 = *(const float4*)(xp + 28);
  }

  for (int k = 0; k < NWIN; ++k) {
    const int cur = k & 1;
    const int prv = cur ^ 1;
    // ================= P1: wave0 resolves window k; workers park =================
    if (tid < 64) {
      // field_lds is through window k-2; xacc supplies window k-1's cross terms
      double Ival = field_lds[mi] + xacc;
      float mcur = m_lds[mi];          // spins through k-1 (publish-based, no lag)
      xacc = 0.0;
      float finals = 0.0f, finald = 0.0f;
      int conf = -1;
      bool locked = false;
      while (true) {
        float s = (Ival >= mt) ? 1.0f : -1.0f;   // I >= atanh(r) <=> tanh(I) >= r
        float dl = s - mcur;
        unsigned long long mask = __ballot(dl != 0.0f) & 0xFFFFFFFFull;
        mask &= (~0ull) << (conf + 1);
        if (mask == 0) {
          if (!locked) { finals = s; finald = 0.0f; }
          break;
        }
        int f = (int)__builtin_ctzll(mask);      // wave-uniform
        if (!locked && t32 <= f) { finals = s; finald = dl; locked = true; }
        float dl_f = __int_as_float(__builtin_amdgcn_readlane(__float_as_int(dl), f));
        float s_f  = __int_as_float(__builtin_amdgcn_readlane(__float_as_int(s), f));
        int   i_f  = __builtin_amdgcn_readlane(mi, f);
        float4 selS, selX;                        // f uniform -> scalar branches
        switch (f >> 2) {
          case 0: selS = s0; selX = x0; break;  case 1: selS = s1; selX = x1; break;
          case 2: selS = s2; selX = x2; break;  case 3: selS = s3; selX = x3; break;
          case 4: selS = s4; selX = x4; break;  case 5: selS = s5; selX = x5; break;
          case 6: selS = s6; selX = x6; break;  default: selS = s7; selX = x7; break;
        }
        float cS, cX;
        switch (f & 3) {
          case 0: cS = selS.x; cX = selX.x; break;
          case 1: cS = selS.y; cX = selX.y; break;
          case 2: cS = selS.z; cX = selX.z; break;
          default: cS = selS.w; cX = selX.w; break;
        }
        Ival += (double)(cS * dl_f);              // exact product: dl in {-2,2}
        xacc += (double)(cX * dl_f);              // correction for window k+1, lane t32
        if (mi == i_f) mcur = s_f;                // in-window duplicate index
        conf = f;
      }
      // publish: compacted flip list + m updates (last occurrence wins)
      unsigned long long fm = __ballot((tid < WIN) && (finald != 0.0f));
      if (tid < WIN) {
        if (finald != 0.0f) {
          int pos = __popcll(fm & ((1ull << t32) - 1ull));
          pubi_lds[cur][pos] = mi;
          pubd_lds[cur][pos] = finald;
        }
        if (mlo) m_lds[mi] = finals;
        if (tid == 0) pubF_lds[cur] = (int)__popcll(fm);
      }
      // issue G(k+2): rows idx(k+2), ST cols idx(k+2), SX cols idx(k+1)
      {
        int gr = __shfl(p2i, jrow);
        const float* Jg = J + (size_t)gr * N;
#pragma unroll
        for (int q = 0; q < 16; ++q) { int c = __shfl(p2i, half + q); gvS[q] = Jg[c]; }
#pragma unroll
        for (int q = 0; q < 16; ++q) { int c = __shfl(ni, half + q); gvX[q] = Jg[c]; }
      }
      // step-data loads for window k+3; rotate pipeline
      {
        int b3 = (k + 3) * WIN; if (b3 >= STEPS) b3 = 0;   // clamp: unused on tail
        int q3i = idx[b3 + t32];
        double q3t = thr[b3 + t32];
        int q3lo = lastocc[b3 + t32];
        mi = ni;   mt = nt;   mlo = nlo;
        ni = p2i;  nt = p2t;  nlo = p2lo;
        p2i = q3i; p2t = q3t; p2lo = q3lo;
      }
    }
    lgkm_barrier();
    // ================= P2: apply + staging (no serial chain here) =================
    if (tid < 64) {
      // store G(k+2) -> buf[cur] (issued one window ago; wait hides under workers)
      float* dS = &bufST[cur][jrow * SBS + half];
      float* dX = &bufSX[cur][jrow * SBS + half];
      *(float4*)(dS + 0)  = make_float4(gvS[0],  gvS[1],  gvS[2],  gvS[3]);
      *(float4*)(dS + 4)  = make_float4(gvS[4],  gvS[5],  gvS[6],  gvS[7]);
      *(float4*)(dS + 8)  = make_float4(gvS[8],  gvS[9],  gvS[10], gvS[11]);
      *(float4*)(dS + 12) = make_float4(gvS[12], gvS[13], gvS[14], gvS[15]);
      *(float4*)(dX + 0)  = make_float4(gvX[0],  gvX[1],  gvX[2],  gvX[3]);
      *(float4*)(dX + 4)  = make_float4(gvX[4],  gvX[5],  gvX[6],  gvX[7]);
      *(float4*)(dX + 8)  = make_float4(gvX[8],  gvX[9],  gvX[10], gvX[11]);
      *(float4*)(dX + 12) = make_float4(gvX[12], gvX[13], gvX[14], gvX[15]);
      // prefetch fragments for resolve(k+1): ST(k+1) from buf[prv], SX(k+1->k+2)
      // from buf[cur] (just stored; same-wave LDS order + lgkmcnt)
      const float* sp = &bufST[prv][(size_t)t32 * SBS];
      s0 = *(const float4*)(sp + 0);  s1 = *(const float4*)(sp + 4);
      s2 = *(const float4*)(sp + 8);  s3 = *(const float4*)(sp + 12);
      s4 = *(const float4*)(sp + 16); s5 = *(const float4*)(sp + 20);
      s6 = *(const float4*)(sp + 24); s7 = *(const float4*)(sp + 28);
      const float* xp = &bufSX[cur][(size_t)t32 * SBS];
      x0 = *(const float4*)(xp + 0);  x1 = *(const float4*)(xp + 4);
      x2 = *(const float4*)(xp + 8);  x3 = *(const float4*)(xp + 12);
      x4 = *(const float4*)(xp + 16); x5 = *(const float4*)(xp + 20);
      x6 = *(const float4*)(xp + 24); x7 = *(const float4*)(xp + 28);
    } else {
      // ---- FMA-apply window k-1 (rows staged last P2: zero load exposure) ----
      int Fap = pubF_lds[prv];
      if (Fap > 0) {                       // uniform
        float4 d0 = *(const float4*)(pubd_lds[prv] + 0);
        float4 d1 = *(const float4*)(pubd_lds[prv] + 4);
        float4 d2 = *(const float4*)(pubd_lds[prv] + 8);
        float4 d3 = *(const float4*)(pubd_lds[prv] + 12);
        float4 d4 = *(const float4*)(pubd_lds[prv] + 16);
        float4 d5 = *(const float4*)(pubd_lds[prv] + 20);
        float4 d6 = *(const float4*)(pubd_lds[prv] + 24);
        float4 d7 = *(const float4*)(pubd_lds[prv] + 28);
        float dvv[WIN] = {d0.x,d0.y,d0.z,d0.w, d1.x,d1.y,d1.z,d1.w,
                          d2.x,d2.y,d2.z,d2.w, d3.x,d3.y,d3.z,d3.w,
                          d4.x,d4.y,d4.z,d4.w, d5.x,d5.y,d5.z,d5.w,
                          d6.x,d6.y,d6.z,d6.w, d7.x,d7.y,d7.z,d7.w};
        float a0 = 0.f, a1 = 0.f, a2 = 0.f, a3 = 0.f, ax = 0.f;
#pragma unroll
        for (int t = 0; t < WIN; ++t)
          if (t < Fap) {
            a0 += rv[t].x * dvv[t]; a1 += rv[t].y * dvv[t];
            a2 += rv[t].z * dvv[t]; a3 += rv[t].w * dvv[t];
            ax += rxv[t] * dvv[t];
          }
        i0 += (double)a0; i1 += (double)a1;
        i2 += (double)a2; i3 += (double)a3;
        *(double2*)(field_lds + 4 * wid + 0) = make_double2(i0, i1);
        *(double2*)(field_lds + 4 * wid + 2) = make_double2(i2, i3);
        if (isx) { i4 += (double)ax; field_lds[XBASE + wid] = i4; }
      }
      // ---- issue loads for window k's flip rows (consumed next P2) ----
      int Fld = pubF_lds[cur];
      if (Fld > 0) {                       // uniform
        int4 r0i = *(const int4*)(pubi_lds[cur] + 0);
        int4 r1i = *(const int4*)(pubi_lds[cur] + 4);
        int4 r2i = *(const int4*)(pubi_lds[cur] + 8);
        int4 r3i = *(const int4*)(pubi_lds[cur] + 12);
        int4 r4i = *(const int4*)(pubi_lds[cur] + 16);
        int4 r5i = *(const int4*)(pubi_lds[cur] + 20);
        int4 r6i = *(const int4*)(pubi_lds[cur] + 24);
        int4 r7i = *(const int4*)(pubi_lds[cur] + 28);
        int rows[WIN] = {r0i.x,r0i.y,r0i.z,r0i.w, r1i.x,r1i.y,r1i.z,r1i.w,
                         r2i.x,r2i.y,r2i.z,r2i.w, r3i.x,r3i.y,r3i.z,r3i.w,
                         r4i.x,r4i.y,r4i.z,r4i.w, r5i.x,r5i.y,r5i.z,r5i.w,
                         r6i.x,r6i.y,r6i.z,r6i.w, r7i.x,r7i.y,r7i.z,r7i.w};
#pragma unroll
        for (int t = 0; t < WIN; ++t)
          if (t < Fld) rv[t] = *(const float4*)(Jb + (size_t)rows[t] * N);
        if (isx) {
#pragma unroll
          for (int t = 0; t < WIN; ++t)
            if (t < Fld) rxv[t] = Jx[(size_t)rows[t] * N];
        }
      }
    }
    lgkm_barrier();
  }

  __syncthreads();
  ((float4*)out)[tid] = ((const float4*)m_lds)[tid];
}

extern "C" void kernel_launch(void* const* d_in, const int* in_sizes, int n_in,
                              void* d_out, int out_size, void* d_ws, size_t ws_size,
                              hipStream_t stream) {
  const float* J = (const float*)d_in[0];
  const float* h = (const float*)d_in[1];
  const float* m0 = (const float*)d_in[2];
  const int* idx = (const int*)d_in[3];
  const float* u = (const float*)d_in[4];
  float* out = (float*)d_out;

  double* thr = (double*)d_ws;                                        // 16384 f64
  double* I0 = (double*)((char*)d_ws + STEPS * sizeof(double));       // 4096 f64
  int* lastocc = (int*)((char*)d_ws + STEPS * sizeof(double)
                                    + N * sizeof(double));            // 16384 i32

  pre_kernel<<<dim3(STEPS / 256), dim3(256), 0, stream>>>(u, idx, thr, lastocc);
  init_field_kernel<<<dim3(N), dim3(256), 0, stream>>>(J, h, m0, I0);
  pbit_kernel<<<dim3(1), dim3(MBLK), 0, stream>>>(J, m0, idx, thr, lastocc, I0, out);
}

// Round 5
// 2285.437 us; speedup vs baseline: 6.0012x; 6.0012x over previous
//
#include <hip/hip_runtime.h>
#include <math.h>

#define N 4096
#define STEPS 16384
#define WIN 32                 // steps resolved per barrier pair
#define NWIN (STEPS / WIN)
#define MBLK 1024
#define SBS 36   // padded stride (floats) for the 32x32 coupling block (float4-aligned)

// Workgroup barrier that does NOT drain vmcnt (LDS-only ordering between phases).
__device__ __forceinline__ void lgkm_barrier() {
  asm volatile("s_waitcnt lgkmcnt(0)\n\ts_barrier" ::: "memory");
}

// ---- prep: thr[t] = atanh(2u-1) in fp64; samemask[t] = window bits with same idx ----
__global__ __launch_bounds__(256) void pre_kernel(const float* __restrict__ u,
                                                  const int* __restrict__ idx,
                                                  double* __restrict__ thr,
                                                  int* __restrict__ samemask) {
  int t = blockIdx.x * 256 + threadIdx.x;
  if (t < STEPS) {
    float r = 2.0f * u[t] - 1.0f;          // exact same fp32 rounding as reference
    double rd = (double)r;
    thr[t] = 0.5 * log((1.0 + rd) / (1.0 - rd));   // r=-1 -> -inf (tie->+1 matches ref)
    int cbase = t & ~(WIN - 1);
    int my = idx[t];
    unsigned int sm = 0u;
    for (int q = 0; q < WIN; ++q)
      if (idx[cbase + q] == my) sm |= (1u << q);   // includes self bit
    samemask[t] = (int)sm;
  }
}

// ---- initial field: I0[row] = sum_k J[row,k]*m0[k] + h[row], fp64 accumulate ----
__global__ __launch_bounds__(256) void init_field_kernel(const float* __restrict__ J,
                                                         const float* __restrict__ h,
                                                         const float* __restrict__ m0,
                                                         double* __restrict__ I) {
  __shared__ double red[256];
  int row = blockIdx.x;
  const float4* Jr = (const float4*)(J + (size_t)row * N);
  const float4* mv = (const float4*)m0;
  double acc = 0.0;
  for (int q = threadIdx.x; q < N / 4; q += 256) {
    float4 a = Jr[q];
    float4 b = mv[q];
    acc += (double)(a.x * b.x) + (double)(a.y * b.y) +
           (double)(a.z * b.z) + (double)(a.w * b.w);
  }
  red[threadIdx.x] = acc;
  __syncthreads();
  for (int s = 128; s > 0; s >>= 1) {
    if (threadIdx.x < s) red[threadIdx.x] += red[threadIdx.x + s];
    __syncthreads();
  }
  if (threadIdx.x == 0) I[row] = red[0] + (double)h[row];
}

// ---- window-resolved Glauber chain: 1 workgroup, 1024 threads, WIN=32 ----
// Round-3 proven structure; resolve loop replaced with BATCH resolve:
//  per round, finalize the maximal prefix of steps whose decisions are provably
//  invariant under the round's flips (slack > 2*(#flips below) and no earlier
//  same-idx flip candidate), then apply all batch flips with one dense
//  branchless 32-FMA pass (multipliers from ballot masks; no readlane/switch).
// Progress >= 1 flip/round guaranteed; typical window resolves in 1-2 rounds.
__global__ __launch_bounds__(MBLK) void pbit_kernel(const float* __restrict__ J,
                                                    const float* __restrict__ m0,
                                                    const int* __restrict__ idx,
                                                    const double* __restrict__ thr,
                                                    const int* __restrict__ samemask,
                                                    const double* __restrict__ I0,
                                                    float* __restrict__ out) {
  __shared__ __align__(16) double field_lds[N];        // 32 KB master field
  __shared__ __align__(16) float m_lds[N];             // 16 KB spins
  __shared__ __align__(16) float ST_lds[WIN * SBS];    // ST[r*SBS+c] = J[idx[r]][idx[c]] (sym)
  __shared__ __align__(16) int   pubi_lds[WIN];        // compacted flip rows
  __shared__ __align__(16) float pubd_lds[WIN];        // compacted deltas (+/-2)
  __shared__ int pubF_lds;                             // flip count

  const int tid = threadIdx.x;

  // owned field elements 4*tid..4*tid+3: fp64 registers + LDS write-through
  double i0, i1, i2, i3;
  {
    const double* ip = I0 + 4 * tid;
    i0 = ip[0]; i1 = ip[1]; i2 = ip[2]; i3 = ip[3];
    *(double2*)(field_lds + 4 * tid + 0) = make_double2(i0, i1);
    *(double2*)(field_lds + 4 * tid + 2) = make_double2(i2, i3);
  }
  ((float4*)m_lds)[tid] = ((const float4*)m0)[tid];

  const int t32 = tid & 31;      // step slot within window (lanes 32-63 duplicate)
  const int jrow = tid >> 1;     // gather row slot (wave0: 0..31)
  const int half = (tid & 1) * 16;  // gather col half

  // wave0 step-data pipeline (2 windows deep)
  int mi = 0, ni = 0;
  unsigned int msm = 0u, nsm = 0u;
  double mt = 0.0, nt = 0.0;

  if (tid < 64) {
    mi = idx[t32];       mt = thr[t32];       msm = (unsigned int)samemask[t32];
    ni = idx[WIN + t32]; nt = thr[WIN + t32]; nsm = (unsigned int)samemask[WIN + t32];
    // synchronous 32x32 block gather for window 0 (addrs via shfl from mi)
    int r0 = __shfl(mi, jrow);
    const float* Jr = J + (size_t)r0 * N;
#pragma unroll
    for (int q = 0; q < 16; ++q) {
      int c = __shfl(mi, half + q);
      ST_lds[jrow * SBS + half + q] = Jr[c];
    }
  }
  __syncthreads();

  for (int k = 0; k < NWIN; ++k) {
    // ---------------- P1: wave0 resolves 32 steps ----------------
    if (tid < 64) {
      // issue block gather for window k+1 (addrs via shfl from ni; stored after resolve)
      int growv = __shfl(ni, jrow);
      const float* Jg = J + (size_t)growv * N;
      int gc0  = __shfl(ni, half + 0),  gc1  = __shfl(ni, half + 1);
      int gc2  = __shfl(ni, half + 2),  gc3  = __shfl(ni, half + 3);
      int gc4  = __shfl(ni, half + 4),  gc5  = __shfl(ni, half + 5);
      int gc6  = __shfl(ni, half + 6),  gc7  = __shfl(ni, half + 7);
      int gc8  = __shfl(ni, half + 8),  gc9  = __shfl(ni, half + 9);
      int gc10 = __shfl(ni, half + 10), gc11 = __shfl(ni, half + 11);
      int gc12 = __shfl(ni, half + 12), gc13 = __shfl(ni, half + 13);
      int gc14 = __shfl(ni, half + 14), gc15 = __shfl(ni, half + 15);
      float gv0  = Jg[gc0],  gv1  = Jg[gc1],  gv2  = Jg[gc2],  gv3  = Jg[gc3];
      float gv4  = Jg[gc4],  gv5  = Jg[gc5],  gv6  = Jg[gc6],  gv7  = Jg[gc7];
      float gv8  = Jg[gc8],  gv9  = Jg[gc9],  gv10 = Jg[gc10], gv11 = Jg[gc11];
      float gv12 = Jg[gc12], gv13 = Jg[gc13], gv14 = Jg[gc14], gv15 = Jg[gc15];
      // issue step-data loads for window k+2
      int b2 = (k + 2) * WIN; if (b2 >= STEPS) b2 = 0;   // clamp: unused on tail
      int n2i = idx[b2 + t32];
      double n2t = thr[b2 + t32];
      unsigned int n2sm = (unsigned int)samemask[b2 + t32];
      // this window's coupling row, register-resident (symmetry: row j = col j)
      const float* sp = &ST_lds[(size_t)t32 * SBS];
      float4 s0 = *(const float4*)(sp + 0),  s1 = *(const float4*)(sp + 4);
      float4 s2 = *(const float4*)(sp + 8),  s3 = *(const float4*)(sp + 12);
      float4 s4 = *(const float4*)(sp + 16), s5 = *(const float4*)(sp + 20);
      float4 s6 = *(const float4*)(sp + 24), s7 = *(const float4*)(sp + 28);
      double Ival = field_lds[mi];
      float mycur = m_lds[mi];
      const unsigned int below = (1u << t32) - 1u;     // bits strictly below my slot
      float finals = 0.0f, finald = 0.0f;
      unsigned int rem = 0xFFFFFFFFu;
      // ---- batch resolve ----
      while (true) {
        bool sup = (Ival >= mt);                 // I >= atanh(r) <=> tanh(I) >= r
        float s = sup ? 1.0f : -1.0f;
        unsigned int D  = (unsigned int)__ballot(sup);
        unsigned int FL = (unsigned int)__ballot(s != mycur) & rem;
        if (FL == 0u) {                          // all remaining decisions final
          if ((rem >> t32) & 1u) { finals = s; finald = 0.0f; }
          break;
        }
        unsigned int FLb = FL & below;
        int nb = __popc(FLb);
        bool stable = (nb == 0) || (fabs(Ival - mt) > (double)(2 * nb));
        bool safe = (FLb & msm) == 0u;           // no earlier same-idx flip cand
        unsigned int good = (unsigned int)__ballot(stable && safe);
        unsigned int bad = rem & ~good;
        unsigned int pm = bad ? ((1u << __builtin_ctz(bad)) - 1u) : 0xFFFFFFFFu;
        unsigned int fin = rem & pm;             // finalized this round (>=1 flip)
        unsigned int batch = FL & pm;            // flips applied this round
        if ((fin >> t32) & 1u) {
          finals = s;
          finald = (s != mycur) ? (2.0f * s) : 0.0f;
        }
        // dense branchless batch apply: multipliers wave-uniform from masks
        float delta = 0.0f;
#define APQ(q, rq) { float dq = ((batch >> (q)) & 1u) ? (((D >> (q)) & 1u) ? 2.0f : -2.0f) : 0.0f; \
                     delta += (rq) * dq; }
        APQ(0,  s0.x) APQ(1,  s0.y) APQ(2,  s0.z) APQ(3,  s0.w)
        APQ(4,  s1.x) APQ(5,  s1.y) APQ(6,  s1.z) APQ(7,  s1.w)
        APQ(8,  s2.x) APQ(9,  s2.y) APQ(10, s2.z) APQ(11, s2.w)
        APQ(12, s3.x) APQ(13, s3.y) APQ(14, s3.z) APQ(15, s3.w)
        APQ(16, s4.x) APQ(17, s4.y) APQ(18, s4.z) APQ(19, s4.w)
        APQ(20, s5.x) APQ(21, s5.y) APQ(22, s5.z) APQ(23, s5.w)
        APQ(24, s6.x) APQ(25, s6.y) APQ(26, s6.z) APQ(27, s6.w)
        APQ(28, s7.x) APQ(29, s7.y) APQ(30, s7.z) APQ(31, s7.w)
#undef APQ
        Ival += (double)delta;                   // exact-enough: f32 partials -> f64
        if (__popc(batch & msm) & 1) mycur = -mycur;   // parity spin update (incl self)
        rem &= ~pm;
        if (rem == 0u) break;
      }
      // publish: compacted flip list + m updates (last occurrence wins)
      unsigned long long fm = __ballot((tid < WIN) && (finald != 0.0f));
      if (tid < WIN) {
        if (finald != 0.0f) {
          int pos = __popcll(fm & ((1ull << t32) - 1ull));
          pubi_lds[pos] = mi;
          pubd_lds[pos] = finald;
        }
        bool mlo = (msm & (0xFFFFFFFEu << t32)) == 0u;   // no later same-idx step
        if (mlo) m_lds[mi] = finals;
        if (tid == 0) pubF_lds = (int)__popcll(fm);
      }
      // store block for window k+1 (gather waited here, ~resolve-length slack)
      {
        float* dst = &ST_lds[jrow * SBS + half];
        *(float4*)(dst + 0)  = make_float4(gv0, gv1, gv2, gv3);
        *(float4*)(dst + 4)  = make_float4(gv4, gv5, gv6, gv7);
        *(float4*)(dst + 8)  = make_float4(gv8, gv9, gv10, gv11);
        *(float4*)(dst + 12) = make_float4(gv12, gv13, gv14, gv15);
      }
      // rotate step-data pipeline
      mi = ni;  mt = nt;  msm = nsm;
      ni = n2i; nt = n2t; nsm = n2sm;
    }
    lgkm_barrier();

    // ---------------- P2: all threads apply the F flipped rows ----------------
    {
      int F = pubF_lds;
      if (F > 0) {                         // uniform: skip flip-free windows
        const float* Jb = J + 4 * (size_t)tid;
#pragma unroll
        for (int b = 0; b < WIN; b += 8) {
          if (b < F) {                     // uniform
            int4 r1 = *(const int4*)(pubi_lds + b);
            int4 r2 = *(const int4*)(pubi_lds + b + 4);
            float4 d1 = *(const float4*)(pubd_lds + b);
            float4 d2 = *(const float4*)(pubd_lds + b + 4);
            int rr[8] = {r1.x, r1.y, r1.z, r1.w, r2.x, r2.y, r2.z, r2.w};
            float dd[8] = {d1.x, d1.y, d1.z, d1.w, d2.x, d2.y, d2.z, d2.w};
            float4 rv[8];
            // loads first (back-to-back issue, one latency exposure per batch)
#pragma unroll
            for (int t = 0; t < 8; ++t)
              if (b + t < F) rv[t] = *(const float4*)(Jb + (size_t)rr[t] * N);
            float a0 = 0.f, a1 = 0.f, a2 = 0.f, a3 = 0.f;
#pragma unroll
            for (int t = 0; t < 8; ++t)
              if (b + t < F) {
                a0 += rv[t].x * dd[t]; a1 += rv[t].y * dd[t];
                a2 += rv[t].z * dd[t]; a3 += rv[t].w * dd[t];
              }
            // batch-local exact fp32 partials -> fp64 master
            i0 += (double)a0; i1 += (double)a1;
            i2 += (double)a2; i3 += (double)a3;
          }
        }
        *(double2*)(field_lds + 4 * tid + 0) = make_double2(i0, i1);
        *(double2*)(field_lds + 4 * tid + 2) = make_double2(i2, i3);
      }
    }
    lgkm_barrier();
  }

  __syncthreads();
  ((float4*)out)[tid] = ((const float4*)m_lds)[tid];
}

extern "C" void kernel_launch(void* const* d_in, const int* in_sizes, int n_in,
                              void* d_out, int out_size, void* d_ws, size_t ws_size,
                              hipStream_t stream) {
  const float* J = (const float*)d_in[0];
  const float* h = (const float*)d_in[1];
  const float* m0 = (const float*)d_in[2];
  const int* idx = (const int*)d_in[3];
  const float* u = (const float*)d_in[4];
  float* out = (float*)d_out;

  double* thr = (double*)d_ws;                                        // 16384 f64
  double* I0 = (double*)((char*)d_ws + STEPS * sizeof(double));       // 4096 f64
  int* samemask = (int*)((char*)d_ws + STEPS * sizeof(double)
                                     + N * sizeof(double));           // 16384 i32

  pre_kernel<<<dim3(STEPS / 256), dim3(256), 0, stream>>>(u, idx, thr, samemask);
  init_field_kernel<<<dim3(N), dim3(256), 0, stream>>>(J, h, m0, I0);
  pbit_kernel<<<dim3(1), dim3(MBLK), 0, stream>>>(J, m0, idx, thr, samemask, I0, out);
}